// Round 1
// baseline (259.080 us; speedup 1.0000x reference)
//
#include <hip/hip_runtime.h>

// Cost volume: B=4, C=32, H=256, W=256, D=9, G=8, cpg=4
// out[b,g,d,h,w] = mean_{c in group g} var(warp_l, warp_r, feat_ref)
// y offset is 0 => bilinear sample degenerates to 1-D lerp along x.

#define B_ 4
#define C_ 32
#define H_ 256
#define W_ 256
#define D_ 9
#define G_ 8
#define HW_ (H_ * W_)

__constant__ float c_res[9] = {-0.4f, -0.3f, -0.2f, -0.1f, 0.0f,
                                0.1f,  0.2f,  0.3f,  0.4f};

__global__ __launch_bounds__(256) void cost_volume_kernel(
    const float* __restrict__ fref,
    const float* __restrict__ fls,
    const float* __restrict__ frs,
    const float* __restrict__ disp0,
    float* __restrict__ out)
{
    // Block ordering: d innermost so 9 consecutive blocks share the same
    // (b,h) feature rows (96 KB working set) in L1/L2.
    int bid = blockIdx.x;
    int d = bid % D_;
    int t = bid / D_;
    int h = t % H_;
    int b = t / H_;
    int w = threadIdx.x;

    float disp = disp0[(b * H_ + h) * W_ + w] + c_res[d];

    float xl = (float)w + disp;   // left warp:  x_dist = +1
    float xr = (float)w - disp;   // right warp: x_dist = -1

    // Left taps
    float xl0f = floorf(xl);
    int   xl0  = (int)xl0f;
    float wl1  = xl - xl0f;
    float wl0  = 1.0f - wl1;
    // fold validity (zeros padding) into the weights
    float wl0e = (xl0     >= 0 && xl0     <= W_ - 1) ? wl0 : 0.0f;
    float wl1e = (xl0 + 1 >= 0 && xl0 + 1 <= W_ - 1) ? wl1 : 0.0f;
    int il0 = min(max(xl0,     0), W_ - 1);
    int il1 = min(max(xl0 + 1, 0), W_ - 1);

    // Right taps
    float xr0f = floorf(xr);
    int   xr0  = (int)xr0f;
    float wr1  = xr - xr0f;
    float wr0  = 1.0f - wr1;
    float wr0e = (xr0     >= 0 && xr0     <= W_ - 1) ? wr0 : 0.0f;
    float wr1e = (xr0 + 1 >= 0 && xr0 + 1 <= W_ - 1) ? wr1 : 0.0f;
    int ir0 = min(max(xr0,     0), W_ - 1);
    int ir1 = min(max(xr0 + 1, 0), W_ - 1);

    // Row base pointers for channel 0 at row h
    size_t rowbase = ((size_t)b * C_ * H_ + h) * W_;
    const float* refrow = fref + rowbase;
    const float* lsrow  = fls  + rowbase;
    const float* rsrow  = frs  + rowbase;

    float acc[G_];
    #pragma unroll
    for (int g = 0; g < G_; ++g) acc[g] = 0.0f;

    #pragma unroll 8
    for (int c = 0; c < C_; ++c) {
        int coff = c * HW_;
        float fr = refrow[coff + w];
        float l0 = lsrow[coff + il0];
        float l1 = lsrow[coff + il1];
        float r0 = rsrow[coff + ir0];
        float r1 = rsrow[coff + ir1];
        float wl = l0 * wl0e + l1 * wl1e;
        float wr = r0 * wr0e + r1 * wr1e;
        float mu = (wl + wr + fr) * (1.0f / 3.0f);
        float da = wl - mu;
        float db = wr - mu;
        float dc = fr - mu;
        acc[c >> 2] += da * da + db * db + dc * dc;
    }

    // var = acc/3, group mean = /4  => * (1/12)
    size_t hw_off = (size_t)h * W_ + w;
    #pragma unroll
    for (int g = 0; g < G_; ++g) {
        out[((size_t)(b * G_ + g) * D_ + d) * HW_ + hw_off] =
            acc[g] * (1.0f / 12.0f);
    }
}

extern "C" void kernel_launch(void* const* d_in, const int* in_sizes, int n_in,
                              void* d_out, int out_size, void* d_ws, size_t ws_size,
                              hipStream_t stream) {
    const float* fref  = (const float*)d_in[0];
    const float* fls   = (const float*)d_in[1];
    const float* frs   = (const float*)d_in[2];
    const float* disp0 = (const float*)d_in[3];
    float* out = (float*)d_out;

    dim3 grid(B_ * D_ * H_);
    dim3 block(W_);
    cost_volume_kernel<<<grid, block, 0, stream>>>(fref, fls, frs, disp0, out);
}

// Round 2
// 166.515 us; speedup vs baseline: 1.5559x; 1.5559x over previous
//
#include <hip/hip_runtime.h>

// Cost volume: B=4, C=32, H=256, W=256, D=9, G=8, cpg=4
// out[b,g,d,h,w] = mean_{c in group g} var(warp_l, warp_r, feat_ref)
// y offset is 0 => bilinear collapses to 1-D lerp along x.
//
// Key structure: res spans [-0.4, 0.4] (< 1.0), so for a fixed pixel the
// floor(x_d) over all 9 d spans <= 2 consecutive ints => 3 taps per side
// cover every disparity. One thread computes all 9 d values from 7 loads
// per channel (fr + 3 left + 3 right), eliminating the 4x cross-block
// re-fetch seen in R1 (FETCH 398 MB vs 102 MB compulsory: the 9 d-blocks
// scattered across 8 non-coherent XCD L2s).

#define B_ 4
#define C_ 32
#define H_ 256
#define W_ 256
#define D_ 9
#define G_ 8
#define CPG 4
#define HW_ (H_ * W_)

__constant__ float c_res[9] = {-0.4f, -0.3f, -0.2f, -0.1f, 0.0f,
                                0.1f,  0.2f,  0.3f,  0.4f};

__global__ __launch_bounds__(256) void cost_volume_kernel(
    const float* __restrict__ fref,
    const float* __restrict__ fls,
    const float* __restrict__ frs,
    const float* __restrict__ disp0,
    float* __restrict__ out)
{
    int bid = blockIdx.x;
    int g = bid & (G_ - 1);
    int t = bid >> 3;
    int h = t & (H_ - 1);
    int b = t >> 8;
    int w = threadIdx.x;

    float dbase = disp0[((size_t)b * H_ + h) * W_ + w];

    // Per-d lerp params. x_l(d) = w + (dbase + res[d]) is monotone
    // non-decreasing in d, so min floor is at d=0 (left) / d=8 (right),
    // and the span is < 1.0 => floor offset jl/jr in {0,1}.
    int i0l = (int)floorf((float)w + (dbase + c_res[0]));
    int i0r = (int)floorf((float)w - (dbase + c_res[8]));

    float wl0v[D_], wl1v[D_], wr0v[D_], wr1v[D_];
    int jl[D_], jr[D_];
    #pragma unroll
    for (int d = 0; d < D_; ++d) {
        float disp = dbase + c_res[d];
        float xl = (float)w + disp;
        float fl = floorf(xl);
        float w1 = xl - fl;
        wl1v[d] = w1;
        wl0v[d] = 1.0f - w1;
        jl[d] = (int)fl - i0l;

        float xr = (float)w - disp;
        float fr_ = floorf(xr);
        float w1r = xr - fr_;
        wr1v[d] = w1r;
        wr0v[d] = 1.0f - w1r;
        jr[d] = (int)fr_ - i0r;
    }

    // Row base for this group's first channel at row h
    size_t rowbase = ((size_t)b * C_ + g * CPG) * (size_t)HW_ + (size_t)h * W_;
    const float* refrow = fref + rowbase;
    const float* lsrow  = fls  + rowbase;
    const float* rsrow  = frs  + rowbase;

    float acc[D_];
    #pragma unroll
    for (int d = 0; d < D_; ++d) acc[d] = 0.0f;

    #pragma unroll
    for (int cc = 0; cc < CPG; ++cc) {
        int coff = cc * HW_;
        float fr = refrow[coff + w];
        float tl[3], tr[3];
        // Zeros-padding folds into the taps: OOB tap -> 0 contribution.
        #pragma unroll
        for (int k = 0; k < 3; ++k) {
            int il = i0l + k;
            tl[k] = (il >= 0 && il < W_) ? lsrow[coff + il] : 0.0f;
            int ir = i0r + k;
            tr[k] = (ir >= 0 && ir < W_) ? rsrow[coff + ir] : 0.0f;
        }
        #pragma unroll
        for (int d = 0; d < D_; ++d) {
            float la = jl[d] ? tl[1] : tl[0];
            float lb = jl[d] ? tl[2] : tl[1];
            float wl = la * wl0v[d] + lb * wl1v[d];
            float ra = jr[d] ? tr[1] : tr[0];
            float rb = jr[d] ? tr[2] : tr[1];
            float wr = ra * wr0v[d] + rb * wr1v[d];
            float mu = (wl + wr + fr) * (1.0f / 3.0f);
            float da = wl - mu;
            float db = wr - mu;
            float dc = fr - mu;
            acc[d] += da * da + db * db + dc * dc;
        }
    }

    // var = acc/3, group mean = /4 => * (1/12)
    size_t obase = ((size_t)(b * G_ + g) * D_) * HW_ + (size_t)h * W_ + w;
    #pragma unroll
    for (int d = 0; d < D_; ++d) {
        out[obase + (size_t)d * HW_] = acc[d] * (1.0f / 12.0f);
    }
}

extern "C" void kernel_launch(void* const* d_in, const int* in_sizes, int n_in,
                              void* d_out, int out_size, void* d_ws, size_t ws_size,
                              hipStream_t stream) {
    const float* fref  = (const float*)d_in[0];
    const float* fls   = (const float*)d_in[1];
    const float* frs   = (const float*)d_in[2];
    const float* disp0 = (const float*)d_in[3];
    float* out = (float*)d_out;

    dim3 grid(B_ * H_ * G_);
    dim3 block(W_);
    cost_volume_kernel<<<grid, block, 0, stream>>>(fref, fls, frs, disp0, out);
}